// Round 6
// baseline (281.511 us; speedup 1.0000x reference)
//
#include <hip/hip_runtime.h>
#include <cstddef>
#include <cstdint>

typedef __attribute__((ext_vector_type(8))) short short8;
typedef __attribute__((ext_vector_type(4))) float f32x4;

static constexpr int F_IN  = 512;
static constexpr int F_H   = 128;
static constexpr int F_OUT = 40;
static constexpr int F_OP  = 48;   // padded output cols for MFMA

__device__ inline unsigned short f2bf(float f) {
  uint32_t u = __builtin_bit_cast(uint32_t, f);
  u = (u + 0x7FFFu + ((u >> 16) & 1u)) >> 16;
  return (unsigned short)u;
}
__device__ inline float bf2f(uint32_t lo16) {
  return __builtin_bit_cast(float, lo16 << 16);
}
__device__ inline void bf8_to_f32(uint4 u, float* o) {
  o[0] = bf2f(u.x & 0xFFFFu); o[1] = bf2f(u.x >> 16);
  o[2] = bf2f(u.y & 0xFFFFu); o[3] = bf2f(u.y >> 16);
  o[4] = bf2f(u.z & 0xFFFFu); o[5] = bf2f(u.z >> 16);
  o[6] = bf2f(u.w & 0xFFFFu); o[7] = bf2f(u.w >> 16);
}

// ---------------- CSR build ----------------
__global__ void k_zero_i32(int* p, int n) {
  int i = blockIdx.x * blockDim.x + threadIdx.x;
  if (i < n) p[i] = 0;
}

__global__ void k_count(const int* __restrict__ dst, int* __restrict__ cnt, int E) {
  int e = blockIdx.x * blockDim.x + threadIdx.x;
  if (e < E) atomicAdd(&cnt[dst[e]], 1);
}

__global__ void k_scan_local(const int* __restrict__ cnt, int* __restrict__ rp,
                             int* __restrict__ bsum, int N) {
  __shared__ int tmp[1024];
  int t = threadIdx.x;
  int i = blockIdx.x * 1024 + t;
  int v = (i < N) ? cnt[i] : 0;
  tmp[t] = v;
  __syncthreads();
  for (int off = 1; off < 1024; off <<= 1) {
    int u = (t >= off) ? tmp[t - off] : 0;
    __syncthreads();
    tmp[t] += u;
    __syncthreads();
  }
  if (i < N) rp[i] = tmp[t] - v;
  if (t == 1023) bsum[blockIdx.x] = tmp[1023];
}

// wave-parallel exclusive scan of block sums (nb <= 64)
__global__ void k_scan_carry(int* bsum, int nb) {
  int l = threadIdx.x;
  int v = (l < nb) ? bsum[l] : 0;
  int orig = v;
  for (int off = 1; off < 64; off <<= 1) {
    int u = __shfl_up(v, off);
    if (l >= off) v += u;
  }
  if (l < nb) bsum[l] = v - orig;
}

// finalize row_ptr, seed scatter cursor with row starts, compute dinv
__global__ void k_scan_add(int* __restrict__ rp, const int* __restrict__ bsum,
                           const int* __restrict__ cnt, int* __restrict__ cursor,
                           float* __restrict__ dinv, int N, int E) {
  int i = blockIdx.x * blockDim.x + threadIdx.x;
  if (i < N) {
    int r = rp[i] + bsum[i >> 10];
    rp[i] = r;
    cursor[i] = r;
    dinv[i] = rsqrtf((float)cnt[i] + 1.0f);
  }
  if (i == N) rp[N] = E;
}

__global__ void k_scatter(const int* __restrict__ src, const int* __restrict__ dst,
                          int* __restrict__ cursor, int* __restrict__ src_sorted, int E) {
  int e = blockIdx.x * blockDim.x + threadIdx.x;
  if (e >= E) return;
  int d = dst[e];
  int pos = atomicAdd(&cursor[d], 1);
  src_sorted[pos] = src[e];
}

// ---------------- weights: W1->W1t[128][512] bf16, W2->W2t[48][128] bf16 ----
__global__ void k_wconv(const float* __restrict__ W1, const float* __restrict__ W2,
                        unsigned short* __restrict__ W1t, unsigned short* __restrict__ W2t) {
  int i = blockIdx.x * blockDim.x + threadIdx.x;
  if (i < F_H * F_IN) {
    int f = i >> 9, k = i & 511;
    W1t[i] = f2bf(W1[(size_t)k * F_H + f]);
  } else {
    int j = i - F_H * F_IN;
    if (j < F_OP * F_H) {
      int c = j >> 7, k = j & 127;
      float v = (c < F_OUT) ? W2[(size_t)k * F_OUT + c] : 0.f;
      W2t[j] = f2bf(v);
    }
  }
}

// ---------------- GEMM1 (MFMA bf16, no LDS, no barriers) -------------------
// 1 wave = 16 rows x 128 cols; A direct from x (f32->bf16 in regs);
// B direct from L2-resident W1t. acc 1x8 f32x4.
__global__ __launch_bounds__(256) void k_gemm1(const float* __restrict__ x,
                                               const unsigned short* __restrict__ Wt,
                                               unsigned short* __restrict__ h, int N) {
  const int t = threadIdx.x, lane = t & 63, w = t >> 6;
  const int l16 = lane & 15, g = lane >> 4;
  const int wave_id = blockIdx.x * 4 + w;
  const int row0 = wave_id * 16;

  int arow = row0 + l16; if (arow >= N) arow = N - 1;
  const float* ap = x + (size_t)arow * F_IN + g * 8;   // +ks*32 +kt*64

  f32x4 acc[8];
#pragma unroll
  for (int j = 0; j < 8; ++j) acc[j] = (f32x4){0.f, 0.f, 0.f, 0.f};

  const unsigned short* bp = Wt + (size_t)l16 * F_IN + g * 8;  // +fc*16*512 +ks*32 +kt*64

  for (int kt = 0; kt < 8; ++kt) {
    const int kb = kt * 64;
    // A fragments (ks = 0,1)
    float4 a0l = *(const float4*)(ap + kb);
    float4 a0h = *(const float4*)(ap + kb + 4);
    float4 a1l = *(const float4*)(ap + kb + 32);
    float4 a1h = *(const float4*)(ap + kb + 36);
    short8 af0, af1;
    af0[0] = (short)f2bf(a0l.x); af0[1] = (short)f2bf(a0l.y);
    af0[2] = (short)f2bf(a0l.z); af0[3] = (short)f2bf(a0l.w);
    af0[4] = (short)f2bf(a0h.x); af0[5] = (short)f2bf(a0h.y);
    af0[6] = (short)f2bf(a0h.z); af0[7] = (short)f2bf(a0h.w);
    af1[0] = (short)f2bf(a1l.x); af1[1] = (short)f2bf(a1l.y);
    af1[2] = (short)f2bf(a1l.z); af1[3] = (short)f2bf(a1l.w);
    af1[4] = (short)f2bf(a1h.x); af1[5] = (short)f2bf(a1h.y);
    af1[6] = (short)f2bf(a1h.z); af1[7] = (short)f2bf(a1h.w);

    // B fragments + MFMA
#pragma unroll
    for (int fc = 0; fc < 8; ++fc) {
      const unsigned short* bq = bp + (size_t)fc * 16 * F_IN + kb;
      short8 b0 = *(const short8*)(bq);
      short8 b1 = *(const short8*)(bq + 32);
      acc[fc] = __builtin_amdgcn_mfma_f32_16x16x32_bf16(af0, b0, acc[fc], 0, 0, 0);
      acc[fc] = __builtin_amdgcn_mfma_f32_16x16x32_bf16(af1, b1, acc[fc], 0, 0, 0);
    }
  }

  int rbase = row0 + g * 4;
#pragma unroll
  for (int fc = 0; fc < 8; ++fc) {
    int col = fc * 16 + l16;
#pragma unroll
    for (int j = 0; j < 4; ++j) {
      int r = rbase + j;
      if (r < N) h[(size_t)r * F_H + col] = f2bf(acc[fc][j]);
    }
  }
}

// ---------------- CSR gather agg bf16->bf16, batched-index MLP -------------
// 16 lanes/node. Batch: 16 src idx + dinv loaded cooperatively, broadcast by
// shfl; the 16 h-row gathers are address-independent -> deep MLP.
template <bool BIAS_RELU>
__global__ void k_agg(const unsigned short* __restrict__ h, const float* __restrict__ dinv,
                      const int* __restrict__ rp, const int* __restrict__ srcs,
                      const float* __restrict__ bias, unsigned short* __restrict__ out, int N) {
  int gid = blockIdx.x * blockDim.x + threadIdx.x;
  int n = gid >> 4;
  if (n >= N) return;
  const int lane = threadIdx.x & 63;
  const int l16 = lane & 15;
  const int gbase = lane & 48;
  const int f = l16 * 8;

  float dn = dinv[n];
  float acc[8], tmp[8];
  uint4 sv = *(const uint4*)(h + (size_t)n * F_H + f);
  bf8_to_f32(sv, tmp);
  float sl = dn * dn;
#pragma unroll
  for (int i = 0; i < 8; ++i) acc[i] = tmp[i] * sl;

  int beg = rp[n], end = rp[n + 1];
  for (int jb = beg; jb < end; jb += 16) {
    int lim = end - jb; if (lim > 16) lim = 16;
    int sidx = srcs[jb + ((l16 < lim) ? l16 : 0)];
    float sdv = dinv[sidx];

    if (lim == 16) {
#pragma unroll
      for (int i = 0; i < 16; ++i) {
        int s = __shfl(sidx, gbase + i);
        float nr = __shfl(sdv, gbase + i) * dn;
        uint4 hv = *(const uint4*)(h + (size_t)s * F_H + f);
        bf8_to_f32(hv, tmp);
#pragma unroll
        for (int q = 0; q < 8; ++q) acc[q] += tmp[q] * nr;
      }
    } else {
      for (int i = 0; i < lim; ++i) {
        int s = __shfl(sidx, gbase + i);
        float nr = __shfl(sdv, gbase + i) * dn;
        uint4 hv = *(const uint4*)(h + (size_t)s * F_H + f);
        bf8_to_f32(hv, tmp);
#pragma unroll
        for (int q = 0; q < 8; ++q) acc[q] += tmp[q] * nr;
      }
    }
  }

  if (BIAS_RELU) {
#pragma unroll
    for (int i = 0; i < 8; ++i) {
      acc[i] += bias[f + i];
      acc[i] = fmaxf(acc[i], 0.f);
    }
  }
  uint4 o;
  o.x = f2bf(acc[0]) | ((unsigned)f2bf(acc[1]) << 16);
  o.y = f2bf(acc[2]) | ((unsigned)f2bf(acc[3]) << 16);
  o.z = f2bf(acc[4]) | ((unsigned)f2bf(acc[5]) << 16);
  o.w = f2bf(acc[6]) | ((unsigned)f2bf(acc[7]) << 16);
  *(uint4*)(out + (size_t)n * F_H + f) = o;
}

// ---------------- GEMM2 (MFMA bf16) + b2 + log_softmax fused ---------------
// out = log_softmax(g2 @ W2 + b2). 4 waves x 32 rows/wave.
__global__ __launch_bounds__(256) void k_gemm2(const unsigned short* __restrict__ a,
                                               const unsigned short* __restrict__ W2t,
                                               const float* __restrict__ b2,
                                               float* __restrict__ out, int N) {
  const int t = threadIdx.x, lane = t & 63, w = t >> 6;
  const int l16 = lane & 15, g = lane >> 4;
  const int row0 = blockIdx.x * 128 + w * 32;

  short8 bfr[3][4];
#pragma unroll
  for (int fc = 0; fc < 3; ++fc)
#pragma unroll
    for (int ks = 0; ks < 4; ++ks)
      bfr[fc][ks] = *(const short8*)(W2t + (size_t)(fc * 16 + l16) * F_H + ks * 32 + g * 8);

  f32x4 acc[2][3];
#pragma unroll
  for (int i = 0; i < 2; ++i)
#pragma unroll
    for (int j = 0; j < 3; ++j) acc[i][j] = (f32x4){0.f, 0.f, 0.f, 0.f};

  short8 af[2][4];
#pragma unroll
  for (int fr = 0; fr < 2; ++fr) {
    int r = row0 + fr * 16 + l16; if (r >= N) r = N - 1;
#pragma unroll
    for (int ks = 0; ks < 4; ++ks)
      af[fr][ks] = *(const short8*)(a + (size_t)r * F_H + ks * 32 + g * 8);
  }

#pragma unroll
  for (int fr = 0; fr < 2; ++fr)
#pragma unroll
    for (int ks = 0; ks < 4; ++ks)
#pragma unroll
      for (int fc = 0; fc < 3; ++fc)
        acc[fr][fc] = __builtin_amdgcn_mfma_f32_16x16x32_bf16(af[fr][ks], bfr[fc][ks], acc[fr][fc], 0, 0, 0);

  // epilogue: +b2, then row-wise log_softmax (reduce over 16 lanes x 3 regs)
  float b0 = b2[l16], b1 = b2[16 + l16];
  float b2v = (l16 < 8) ? b2[32 + l16] : 0.f;

#pragma unroll
  for (int fr = 0; fr < 2; ++fr) {
#pragma unroll
    for (int j = 0; j < 4; ++j) {
      int r = row0 + fr * 16 + g * 4 + j;   // uniform across the 16 reducing lanes
      if (r >= N) continue;
      float v0 = acc[fr][0][j] + b0;
      float v1 = acc[fr][1][j] + b1;
      float v2 = (l16 < 8) ? (acc[fr][2][j] + b2v) : -3.0e38f;
      float m = fmaxf(fmaxf(v0, v1), v2);
#pragma unroll
      for (int off = 8; off > 0; off >>= 1) m = fmaxf(m, __shfl_xor(m, off));
      float e = expf(v0 - m) + expf(v1 - m) + ((l16 < 8) ? expf(v2 - m) : 0.f);
#pragma unroll
      for (int off = 8; off > 0; off >>= 1) e += __shfl_xor(e, off);
      float ls = logf(e);
      float* orow = out + (size_t)r * F_OUT;
      orow[l16] = v0 - m - ls;
      orow[16 + l16] = v1 - m - ls;
      if (l16 < 8) orow[32 + l16] = v2 - m - ls;
    }
  }
}

extern "C" void kernel_launch(void* const* d_in, const int* in_sizes, int n_in,
                              void* d_out, int out_size, void* d_ws, size_t ws_size,
                              hipStream_t stream) {
  const float* x  = (const float*)d_in[0];
  const int*   ei = (const int*)d_in[1];
  const float* W1 = (const float*)d_in[2];
  const float* b1 = (const float*)d_in[3];
  const float* W2 = (const float*)d_in[4];
  const float* b2 = (const float*)d_in[5];

  const int N = in_sizes[0] / F_IN;   // 50000
  const int E = in_sizes[1] / 2;      // 800000
  const int* src = ei;
  const int* dst = ei + E;

  // workspace layout (4-byte words)
  float* ws   = (float*)d_ws;
  size_t Npad = ((size_t)N + 1023) & ~(size_t)1023;
  float*          dinv   = ws;
  unsigned short* h1b    = (unsigned short*)(ws + Npad);          // N*128 bf16
  unsigned short* a1b    = h1b + (size_t)N * F_H;                 // N*128 bf16
  unsigned short* g2b    = a1b + (size_t)N * F_H;                 // N*128 bf16
  int*            cnt    = (int*)(g2b + (size_t)N * F_H);
  int*            row_ptr= cnt + Npad;
  int*            cursor = row_ptr + Npad;
  int*            src_sorted = cursor + Npad;
  unsigned short* W1t    = (unsigned short*)(src_sorted + E);     // 128*512 bf16
  unsigned short* W2t    = W1t + (size_t)F_H * F_IN;              // 48*128 bf16
  int*            bsum   = (int*)(W2t + (size_t)F_OP * F_H);
  float*          outp   = (float*)d_out;

  const int B = 256;
  const int nscan = (N + 1023) / 1024;   // 49

  k_zero_i32  <<<(N + B - 1) / B, B, 0, stream>>>(cnt, N);
  k_count     <<<(E + B - 1) / B, B, 0, stream>>>(dst, cnt, E);
  k_scan_local<<<nscan, 1024, 0, stream>>>(cnt, row_ptr, bsum, N);
  k_scan_carry<<<1, 64, 0, stream>>>(bsum, nscan);
  k_scan_add  <<<(N + 1 + B - 1) / B, B, 0, stream>>>(row_ptr, bsum, cnt, cursor, dinv, N, E);
  k_scatter   <<<(E + B - 1) / B, B, 0, stream>>>(src, dst, cursor, src_sorted, E);

  k_wconv<<<(F_H * F_IN + F_OP * F_H + B - 1) / B, B, 0, stream>>>(W1, W2, W1t, W2t);

  // layer 1
  k_gemm1<<<(N + 63) / 64, 256, 0, stream>>>(x, W1t, h1b, N);
  {
    long long threads = (long long)N * 16;
    k_agg<true><<<(int)((threads + B - 1) / B), B, 0, stream>>>(h1b, dinv, row_ptr, src_sorted, b1, a1b, N);
  }

  // layer 2: aggregate first ((A a1) W2 == A (a1 W2)), then GEMM+softmax
  {
    long long threads = (long long)N * 16;
    k_agg<false><<<(int)((threads + B - 1) / B), B, 0, stream>>>(a1b, dinv, row_ptr, src_sorted, nullptr, g2b, N);
  }
  k_gemm2<<<(N + 127) / 128, 256, 0, stream>>>(g2b, W2t, b2, outp, N);
}

// Round 7
// 229.202 us; speedup vs baseline: 1.2282x; 1.2282x over previous
//
#include <hip/hip_runtime.h>
#include <hip/hip_bf16.h>
#include <cstddef>
#include <cstdint>

typedef __attribute__((ext_vector_type(8))) short short8;
typedef __attribute__((ext_vector_type(4))) float f32x4;

static constexpr int F_IN  = 512;
static constexpr int F_H   = 128;
static constexpr int F_OUT = 40;
static constexpr int F_OP  = 48;   // padded output cols for MFMA

__device__ inline unsigned short f2bf(float f) {
  return __builtin_bit_cast(unsigned short, __float2bfloat16(f));
}
__device__ inline float bf2f(uint32_t lo16) {
  return __builtin_bit_cast(float, lo16 << 16);
}
__device__ inline void bf8_to_f32(uint4 u, float* o) {
  o[0] = bf2f(u.x & 0xFFFFu); o[1] = bf2f(u.x >> 16);
  o[2] = bf2f(u.y & 0xFFFFu); o[3] = bf2f(u.y >> 16);
  o[4] = bf2f(u.z & 0xFFFFu); o[5] = bf2f(u.z >> 16);
  o[6] = bf2f(u.w & 0xFFFFu); o[7] = bf2f(u.w >> 16);
}
__device__ inline void gload_lds16(const void* g, void* l) {
  __builtin_amdgcn_global_load_lds(
      (const __attribute__((address_space(1))) void*)g,
      (__attribute__((address_space(3))) void*)l, 16, 0, 0);
}

// ---------------- CSR build ----------------
__global__ void k_zero_i32(int* p, int n) {
  int i = blockIdx.x * blockDim.x + threadIdx.x;
  if (i < n) p[i] = 0;
}

__global__ void k_count(const int* __restrict__ dst, int* __restrict__ cnt, int E) {
  int e = blockIdx.x * blockDim.x + threadIdx.x;
  if (e < E) atomicAdd(&cnt[dst[e]], 1);
}

__global__ void k_scan_local(const int* __restrict__ cnt, int* __restrict__ rp,
                             int* __restrict__ bsum, int N) {
  __shared__ int tmp[1024];
  int t = threadIdx.x;
  int i = blockIdx.x * 1024 + t;
  int v = (i < N) ? cnt[i] : 0;
  tmp[t] = v;
  __syncthreads();
  for (int off = 1; off < 1024; off <<= 1) {
    int u = (t >= off) ? tmp[t - off] : 0;
    __syncthreads();
    tmp[t] += u;
    __syncthreads();
  }
  if (i < N) rp[i] = tmp[t] - v;
  if (t == 1023) bsum[blockIdx.x] = tmp[1023];
}

// wave-parallel exclusive scan of block sums (nb <= 64)
__global__ void k_scan_carry(int* bsum, int nb) {
  int l = threadIdx.x;
  int v = (l < nb) ? bsum[l] : 0;
  int orig = v;
  for (int off = 1; off < 64; off <<= 1) {
    int u = __shfl_up(v, off);
    if (l >= off) v += u;
  }
  if (l < nb) bsum[l] = v - orig;
}

// finalize row_ptr, seed scatter cursor with row starts, compute dinv
__global__ void k_scan_add(int* __restrict__ rp, const int* __restrict__ bsum,
                           const int* __restrict__ cnt, int* __restrict__ cursor,
                           float* __restrict__ dinv, int N, int E) {
  int i = blockIdx.x * blockDim.x + threadIdx.x;
  if (i < N) {
    int r = rp[i] + bsum[i >> 10];
    rp[i] = r;
    cursor[i] = r;
    dinv[i] = rsqrtf((float)cnt[i] + 1.0f);
  }
  if (i == N) rp[N] = E;
}

__global__ void k_scatter(const int* __restrict__ src, const int* __restrict__ dst,
                          int* __restrict__ cursor, int* __restrict__ src_sorted, int E) {
  int e = blockIdx.x * blockDim.x + threadIdx.x;
  if (e >= E) return;
  int d = dst[e];
  int pos = atomicAdd(&cursor[d], 1);
  src_sorted[pos] = src[e];
}

// ---------------- weights: W1->W1t[128][512] bf16, W2->W2t[48][128] bf16 ----
__global__ void k_wconv(const float* __restrict__ W1, const float* __restrict__ W2,
                        unsigned short* __restrict__ W1t, unsigned short* __restrict__ W2t) {
  int i = blockIdx.x * blockDim.x + threadIdx.x;
  if (i < F_H * F_IN) {
    int f = i >> 9, k = i & 511;
    W1t[i] = f2bf(W1[(size_t)k * F_H + f]);
  } else {
    int j = i - F_H * F_IN;
    if (j < F_OP * F_H) {
      int c = j >> 7, k = j & 127;
      float v = (c < F_OUT) ? W2[(size_t)k * F_OUT + c] : 0.f;
      W2t[j] = f2bf(v);
    }
  }
}

// ---------------- GEMM1 (MFMA bf16): h = x @ W1 ----------------------------
// BM=128, BN=128, BK=64; 4 waves x 32 rows. A: direct-from-global per lane
// (rows are wave-private), f32->bf16 in regs. B: global_load_lds(16B) into
// XOR-chunk-swizzled double-buffered LDS (source carries inverse swizzle).
__global__ __launch_bounds__(256) void k_gemm1(const float* __restrict__ x,
                                               const unsigned short* __restrict__ Wt,
                                               unsigned short* __restrict__ h, int N) {
  __shared__ unsigned short Bt[2][128][64];   // 32 KB
  const int t = threadIdx.x, lane = t & 63, w = t >> 6;
  const int l16 = lane & 15, g = lane >> 4;
  const int row0 = blockIdx.x * 128;

  // B staging: wave w, rep r covers rows r*32+w*8 .. +7 (linear 1KB DMA).
  // lane writes physical chunk (lane&7) of row rg+(lane>>3); source chunk is
  // the inverse swizzle lc = (lane&7) ^ (row&7).
  int bsrow[4], bslc[4];
#pragma unroll
  for (int r = 0; r < 4; ++r) {
    int rg = r * 32 + w * 8;
    bsrow[r] = rg + (lane >> 3);
    bslc[r]  = (lane & 7) ^ (bsrow[r] & 7);
  }

  // A rows (2 fragment rows per lane, wave-private)
  int ar0 = row0 + w * 32 + l16;      if (ar0 >= N) ar0 = N - 1;
  int ar1 = row0 + w * 32 + 16 + l16; if (ar1 >= N) ar1 = N - 1;
  const float* ap0 = x + (size_t)ar0 * F_IN + g * 8;
  const float* ap1 = x + (size_t)ar1 * F_IN + g * 8;

  f32x4 acc[2][8];
#pragma unroll
  for (int i = 0; i < 2; ++i)
#pragma unroll
    for (int j = 0; j < 8; ++j) acc[i][j] = (f32x4){0.f, 0.f, 0.f, 0.f};

  auto issueB = [&](int buf, int k0) {
#pragma unroll
    for (int r = 0; r < 4; ++r)
      gload_lds16(Wt + (size_t)bsrow[r] * F_IN + k0 + bslc[r] * 8,
                  &Bt[buf][r * 32 + w * 8][0]);
  };

  issueB(0, 0);
  __syncthreads();

  for (int kt = 0; kt < 8; ++kt) {
    const int cur = kt & 1;
    if (kt < 7) issueB(cur ^ 1, (kt + 1) * 64);

    // A fragments, f32 -> bf16 in registers
    short8 af[2][2];
#pragma unroll
    for (int fr = 0; fr < 2; ++fr)
#pragma unroll
      for (int ks = 0; ks < 2; ++ks) {
        const float* p = (fr ? ap1 : ap0) + kt * 64 + ks * 32;
        float4 lo = *(const float4*)p;
        float4 hi = *(const float4*)(p + 4);
        short8 v;
        v[0] = (short)f2bf(lo.x); v[1] = (short)f2bf(lo.y);
        v[2] = (short)f2bf(lo.z); v[3] = (short)f2bf(lo.w);
        v[4] = (short)f2bf(hi.x); v[5] = (short)f2bf(hi.y);
        v[6] = (short)f2bf(hi.z); v[7] = (short)f2bf(hi.w);
        af[fr][ks] = v;
      }

#pragma unroll
    for (int ks = 0; ks < 2; ++ks) {
      const int lcf = ks * 4 + g;
      short8 bfr[8];
#pragma unroll
      for (int fc = 0; fc < 8; ++fc) {
        int rr = fc * 16 + l16;
        bfr[fc] = *(const short8*)&Bt[cur][rr][(lcf ^ (rr & 7)) * 8];
      }
#pragma unroll
      for (int fr = 0; fr < 2; ++fr)
#pragma unroll
        for (int fc = 0; fc < 8; ++fc)
          acc[fr][fc] = __builtin_amdgcn_mfma_f32_16x16x32_bf16(af[fr][ks], bfr[fc], acc[fr][fc], 0, 0, 0);
    }
    __syncthreads();
  }

  // C write (bf16): col = fc*16 + l16, row = row0 + w*32 + fr*16 + g*4 + j
#pragma unroll
  for (int fr = 0; fr < 2; ++fr) {
    int rbase = row0 + w * 32 + fr * 16 + g * 4;
#pragma unroll
    for (int fc = 0; fc < 8; ++fc) {
      int col = fc * 16 + l16;
#pragma unroll
      for (int j = 0; j < 4; ++j) {
        int r = rbase + j;
        if (r < N) h[(size_t)r * F_H + col] = f2bf(acc[fr][fc][j]);
      }
    }
  }
}

// ---------------- CSR gather agg bf16->bf16, batched-index MLP -------------
template <bool BIAS_RELU>
__global__ void k_agg(const unsigned short* __restrict__ h, const float* __restrict__ dinv,
                      const int* __restrict__ rp, const int* __restrict__ srcs,
                      const float* __restrict__ bias, unsigned short* __restrict__ out, int N) {
  int gid = blockIdx.x * blockDim.x + threadIdx.x;
  int n = gid >> 4;
  if (n >= N) return;
  const int lane = threadIdx.x & 63;
  const int l16 = lane & 15;
  const int gbase = lane & 48;
  const int f = l16 * 8;

  float dn = dinv[n];
  float acc[8], tmp[8];
  uint4 sv = *(const uint4*)(h + (size_t)n * F_H + f);
  bf8_to_f32(sv, tmp);
  float sl = dn * dn;
#pragma unroll
  for (int i = 0; i < 8; ++i) acc[i] = tmp[i] * sl;

  int beg = rp[n], end = rp[n + 1];
  for (int jb = beg; jb < end; jb += 16) {
    int lim = end - jb; if (lim > 16) lim = 16;
    int sidx = srcs[jb + ((l16 < lim) ? l16 : 0)];
    float sdv = dinv[sidx];

    if (lim == 16) {
#pragma unroll
      for (int i = 0; i < 16; ++i) {
        int s = __shfl(sidx, gbase + i);
        float nr = __shfl(sdv, gbase + i) * dn;
        uint4 hv = *(const uint4*)(h + (size_t)s * F_H + f);
        bf8_to_f32(hv, tmp);
#pragma unroll
        for (int q = 0; q < 8; ++q) acc[q] += tmp[q] * nr;
      }
    } else {
      for (int i = 0; i < lim; ++i) {
        int s = __shfl(sidx, gbase + i);
        float nr = __shfl(sdv, gbase + i) * dn;
        uint4 hv = *(const uint4*)(h + (size_t)s * F_H + f);
        bf8_to_f32(hv, tmp);
#pragma unroll
        for (int q = 0; q < 8; ++q) acc[q] += tmp[q] * nr;
      }
    }
  }

  if (BIAS_RELU) {
#pragma unroll
    for (int i = 0; i < 8; ++i) {
      acc[i] += bias[f + i];
      acc[i] = fmaxf(acc[i], 0.f);
    }
  }
  uint4 o;
  o.x = f2bf(acc[0]) | ((unsigned)f2bf(acc[1]) << 16);
  o.y = f2bf(acc[2]) | ((unsigned)f2bf(acc[3]) << 16);
  o.z = f2bf(acc[4]) | ((unsigned)f2bf(acc[5]) << 16);
  o.w = f2bf(acc[6]) | ((unsigned)f2bf(acc[7]) << 16);
  *(uint4*)(out + (size_t)n * F_H + f) = o;
}

// ---------------- GEMM2 (MFMA bf16) + b2 + log_softmax fused ---------------
__global__ __launch_bounds__(256) void k_gemm2(const unsigned short* __restrict__ a,
                                               const unsigned short* __restrict__ W2t,
                                               const float* __restrict__ b2,
                                               float* __restrict__ out, int N) {
  const int t = threadIdx.x, lane = t & 63, w = t >> 6;
  const int l16 = lane & 15, g = lane >> 4;
  const int row0 = blockIdx.x * 128 + w * 32;

  short8 bfr[3][4];
#pragma unroll
  for (int fc = 0; fc < 3; ++fc)
#pragma unroll
    for (int ks = 0; ks < 4; ++ks)
      bfr[fc][ks] = *(const short8*)(W2t + (size_t)(fc * 16 + l16) * F_H + ks * 32 + g * 8);

  f32x4 acc[2][3];
#pragma unroll
  for (int i = 0; i < 2; ++i)
#pragma unroll
    for (int j = 0; j < 3; ++j) acc[i][j] = (f32x4){0.f, 0.f, 0.f, 0.f};

  short8 af[2][4];
#pragma unroll
  for (int fr = 0; fr < 2; ++fr) {
    int r = row0 + fr * 16 + l16; if (r >= N) r = N - 1;
#pragma unroll
    for (int ks = 0; ks < 4; ++ks)
      af[fr][ks] = *(const short8*)(a + (size_t)r * F_H + ks * 32 + g * 8);
  }

#pragma unroll
  for (int fr = 0; fr < 2; ++fr)
#pragma unroll
    for (int ks = 0; ks < 4; ++ks)
#pragma unroll
      for (int fc = 0; fc < 3; ++fc)
        acc[fr][fc] = __builtin_amdgcn_mfma_f32_16x16x32_bf16(af[fr][ks], bfr[fc][ks], acc[fr][fc], 0, 0, 0);

  // epilogue: +b2, then row-wise log_softmax (reduce over 16 lanes x 3 regs)
  float b0 = b2[l16], b1 = b2[16 + l16];
  float b2v = (l16 < 8) ? b2[32 + l16] : 0.f;

#pragma unroll
  for (int fr = 0; fr < 2; ++fr) {
#pragma unroll
    for (int j = 0; j < 4; ++j) {
      int r = row0 + fr * 16 + g * 4 + j;   // uniform across the 16 reducing lanes
      if (r >= N) continue;
      float v0 = acc[fr][0][j] + b0;
      float v1 = acc[fr][1][j] + b1;
      float v2 = (l16 < 8) ? (acc[fr][2][j] + b2v) : -3.0e38f;
      float m = fmaxf(fmaxf(v0, v1), v2);
#pragma unroll
      for (int off = 8; off > 0; off >>= 1) m = fmaxf(m, __shfl_xor(m, off));
      float e = expf(v0 - m) + expf(v1 - m) + ((l16 < 8) ? expf(v2 - m) : 0.f);
#pragma unroll
      for (int off = 8; off > 0; off >>= 1) e += __shfl_xor(e, off);
      float ls = logf(e);
      float* orow = out + (size_t)r * F_OUT;
      orow[l16] = v0 - m - ls;
      orow[16 + l16] = v1 - m - ls;
      if (l16 < 8) orow[32 + l16] = v2 - m - ls;
    }
  }
}

extern "C" void kernel_launch(void* const* d_in, const int* in_sizes, int n_in,
                              void* d_out, int out_size, void* d_ws, size_t ws_size,
                              hipStream_t stream) {
  const float* x  = (const float*)d_in[0];
  const int*   ei = (const int*)d_in[1];
  const float* W1 = (const float*)d_in[2];
  const float* b1 = (const float*)d_in[3];
  const float* W2 = (const float*)d_in[4];
  const float* b2 = (const float*)d_in[5];

  const int N = in_sizes[0] / F_IN;   // 50000
  const int E = in_sizes[1] / 2;      // 800000
  const int* src = ei;
  const int* dst = ei + E;

  // workspace layout (4-byte words)
  float* ws   = (float*)d_ws;
  size_t Npad = ((size_t)N + 1023) & ~(size_t)1023;
  float*          dinv   = ws;
  unsigned short* h1b    = (unsigned short*)(ws + Npad);          // N*128 bf16
  unsigned short* a1b    = h1b + (size_t)N * F_H;                 // N*128 bf16
  unsigned short* g2b    = a1b + (size_t)N * F_H;                 // N*128 bf16
  int*            cnt    = (int*)(g2b + (size_t)N * F_H);
  int*            row_ptr= cnt + Npad;
  int*            cursor = row_ptr + Npad;
  int*            src_sorted = cursor + Npad;
  unsigned short* W1t    = (unsigned short*)(src_sorted + E);     // 128*512 bf16
  unsigned short* W2t    = W1t + (size_t)F_H * F_IN;              // 48*128 bf16
  int*            bsum   = (int*)(W2t + (size_t)F_OP * F_H);
  float*          outp   = (float*)d_out;

  const int B = 256;
  const int nscan = (N + 1023) / 1024;   // 49

  k_zero_i32  <<<(N + B - 1) / B, B, 0, stream>>>(cnt, N);
  k_count     <<<(E + B - 1) / B, B, 0, stream>>>(dst, cnt, E);
  k_scan_local<<<nscan, 1024, 0, stream>>>(cnt, row_ptr, bsum, N);
  k_scan_carry<<<1, 64, 0, stream>>>(bsum, nscan);
  k_scan_add  <<<(N + 1 + B - 1) / B, B, 0, stream>>>(row_ptr, bsum, cnt, cursor, dinv, N, E);
  k_scatter   <<<(E + B - 1) / B, B, 0, stream>>>(src, dst, cursor, src_sorted, E);

  k_wconv<<<(F_H * F_IN + F_OP * F_H + B - 1) / B, B, 0, stream>>>(W1, W2, W1t, W2t);

  // layer 1
  k_gemm1<<<(N + 127) / 128, 256, 0, stream>>>(x, W1t, h1b, N);
  {
    long long threads = (long long)N * 16;
    k_agg<true><<<(int)((threads + B - 1) / B), B, 0, stream>>>(h1b, dinv, row_ptr, src_sorted, b1, a1b, N);
  }

  // layer 2: aggregate first ((A a1) W2 == A (a1 W2)), then GEMM+softmax
  {
    long long threads = (long long)N * 16;
    k_agg<false><<<(int)((threads + B - 1) / B), B, 0, stream>>>(a1b, dinv, row_ptr, src_sorted, nullptr, g2b, N);
  }
  k_gemm2<<<(N + 127) / 128, 256, 0, stream>>>(g2b, W2t, b2, outp, N);
}

// Round 8
// 209.430 us; speedup vs baseline: 1.3442x; 1.0944x over previous
//
#include <hip/hip_runtime.h>
#include <hip/hip_bf16.h>
#include <cstddef>
#include <cstdint>

typedef __attribute__((ext_vector_type(8))) short short8;
typedef __attribute__((ext_vector_type(4))) float f32x4;

static constexpr int F_IN  = 512;
static constexpr int F_H   = 128;
static constexpr int F_OUT = 40;
static constexpr int F_OP  = 48;   // padded cols for gemm2 MFMA
static constexpr int F_PAD = 64;   // h2 row stride (bf16)

__device__ inline unsigned short f2bf(float f) {
  return __builtin_bit_cast(unsigned short, __float2bfloat16(f));
}
__device__ inline float bf2f(uint32_t lo16) {
  return __builtin_bit_cast(float, lo16 << 16);
}
__device__ inline void bf8_to_f32(uint4 u, float* o) {
  o[0] = bf2f(u.x & 0xFFFFu); o[1] = bf2f(u.x >> 16);
  o[2] = bf2f(u.y & 0xFFFFu); o[3] = bf2f(u.y >> 16);
  o[4] = bf2f(u.z & 0xFFFFu); o[5] = bf2f(u.z >> 16);
  o[6] = bf2f(u.w & 0xFFFFu); o[7] = bf2f(u.w >> 16);
}
__device__ inline void gload_lds16(const void* g, void* l) {
  __builtin_amdgcn_global_load_lds(
      (const __attribute__((address_space(1))) void*)g,
      (__attribute__((address_space(3))) void*)l, 16, 0, 0);
}

// ---------------- CSR build ----------------
__global__ void k_count(const int* __restrict__ dst, int* __restrict__ cnt, int E) {
  int e = blockIdx.x * blockDim.x + threadIdx.x;
  if (e < E) atomicAdd(&cnt[dst[e]], 1);
}

__global__ void k_scan_local(const int* __restrict__ cnt, int* __restrict__ rp,
                             int* __restrict__ bsum, int N) {
  __shared__ int tmp[1024];
  int t = threadIdx.x;
  int i = blockIdx.x * 1024 + t;
  int v = (i < N) ? cnt[i] : 0;
  tmp[t] = v;
  __syncthreads();
  for (int off = 1; off < 1024; off <<= 1) {
    int u = (t >= off) ? tmp[t - off] : 0;
    __syncthreads();
    tmp[t] += u;
    __syncthreads();
  }
  if (i < N) rp[i] = tmp[t] - v;
  if (t == 1023) bsum[blockIdx.x] = tmp[1023];
}

// finalize row_ptr (adds block-sum prefix computed redundantly per block),
// seed cursor, compute dinv. nb <= 64.
__global__ void k_scan_add(int* __restrict__ rp, const int* __restrict__ bsum,
                           const int* __restrict__ cnt, int* __restrict__ cursor,
                           float* __restrict__ dinv, int N, int E, int nb) {
  __shared__ int sb[64];
  int t = threadIdx.x;
  if (t < 64) {
    int v = (t < nb) ? bsum[t] : 0;
    int orig = v;
#pragma unroll
    for (int off = 1; off < 64; off <<= 1) {
      int u = __shfl_up(v, off);
      if ((t & 63) >= off) v += u;
    }
    sb[t] = v - orig;   // exclusive prefix
  }
  __syncthreads();
  int i = blockIdx.x * blockDim.x + t;
  if (i < N) {
    int r = rp[i] + sb[i >> 10];
    rp[i] = r;
    cursor[i] = r;
    dinv[i] = rsqrtf((float)cnt[i] + 1.0f);
  }
  if (i == N) rp[N] = E;
}

__global__ void k_scatter(const int* __restrict__ src, const int* __restrict__ dst,
                          int* __restrict__ cursor, int* __restrict__ src_sorted, int E) {
  int e = blockIdx.x * blockDim.x + threadIdx.x;
  if (e >= E) return;
  int d = dst[e];
  int pos = atomicAdd(&cursor[d], 1);
  src_sorted[pos] = src[e];
}

// ---------------- weights: W1->W1t[128][512] bf16, W2->W2t[48][128] bf16 ----
__global__ void k_wconv(const float* __restrict__ W1, const float* __restrict__ W2,
                        unsigned short* __restrict__ W1t, unsigned short* __restrict__ W2t) {
  int i = blockIdx.x * blockDim.x + threadIdx.x;
  if (i < F_H * F_IN) {
    int f = i >> 9, k = i & 511;
    W1t[i] = f2bf(W1[(size_t)k * F_H + f]);
  } else {
    int j = i - F_H * F_IN;
    if (j < F_OP * F_H) {
      int c = j >> 7, k = j & 127;
      float v = (c < F_OUT) ? W2[(size_t)k * F_OUT + c] : 0.f;
      W2t[j] = f2bf(v);
    }
  }
}

// ---------------- GEMM1 (MFMA bf16): h = x @ W1 ----------------------------
// BM=64, BN=128, BK=64; 4 waves x 16 rows (occupancy: 32KB LDS -> 5 blk/CU,
// grid 782 ~ 3 blk/CU resident). A direct-from-global (wave-private rows),
// B via global_load_lds into XOR-swizzled double-buffered LDS.
__global__ __launch_bounds__(256) void k_gemm1(const float* __restrict__ x,
                                               const unsigned short* __restrict__ Wt,
                                               unsigned short* __restrict__ h, int N) {
  __shared__ unsigned short Bt[2][128][64];   // 32 KB
  const int t = threadIdx.x, lane = t & 63, w = t >> 6;
  const int l16 = lane & 15, g = lane >> 4;
  const int row0 = blockIdx.x * 64;

  // B staging: wave w, rep r covers rows r*32+w*8 .. +7 (linear 1KB DMA).
  int bsrow[4], bslc[4];
#pragma unroll
  for (int r = 0; r < 4; ++r) {
    int rg = r * 32 + w * 8;
    bsrow[r] = rg + (lane >> 3);
    bslc[r]  = (lane & 7) ^ (bsrow[r] & 7);
  }

  int ar = row0 + w * 16 + l16; if (ar >= N) ar = N - 1;
  const float* ap = x + (size_t)ar * F_IN + g * 8;

  f32x4 acc[8];
#pragma unroll
  for (int j = 0; j < 8; ++j) acc[j] = (f32x4){0.f, 0.f, 0.f, 0.f};

  auto issueB = [&](int buf, int k0) {
#pragma unroll
    for (int r = 0; r < 4; ++r)
      gload_lds16(Wt + (size_t)bsrow[r] * F_IN + k0 + bslc[r] * 8,
                  &Bt[buf][r * 32 + w * 8][0]);
  };

  issueB(0, 0);
  __syncthreads();

  for (int kt = 0; kt < 8; ++kt) {
    const int cur = kt & 1;
    if (kt < 7) issueB(cur ^ 1, (kt + 1) * 64);

    short8 af[2];
#pragma unroll
    for (int ks = 0; ks < 2; ++ks) {
      const float* p = ap + kt * 64 + ks * 32;
      float4 lo = *(const float4*)p;
      float4 hi = *(const float4*)(p + 4);
      short8 v;
      v[0] = (short)f2bf(lo.x); v[1] = (short)f2bf(lo.y);
      v[2] = (short)f2bf(lo.z); v[3] = (short)f2bf(lo.w);
      v[4] = (short)f2bf(hi.x); v[5] = (short)f2bf(hi.y);
      v[6] = (short)f2bf(hi.z); v[7] = (short)f2bf(hi.w);
      af[ks] = v;
    }

#pragma unroll
    for (int ks = 0; ks < 2; ++ks) {
      const int lcf = ks * 4 + g;
      short8 bfr[8];
#pragma unroll
      for (int fc = 0; fc < 8; ++fc) {
        int rr = fc * 16 + l16;
        bfr[fc] = *(const short8*)&Bt[cur][rr][(lcf ^ (rr & 7)) * 8];
      }
#pragma unroll
      for (int fc = 0; fc < 8; ++fc)
        acc[fc] = __builtin_amdgcn_mfma_f32_16x16x32_bf16(af[ks], bfr[fc], acc[fc], 0, 0, 0);
    }
    __syncthreads();
  }

  int rbase = row0 + w * 16 + g * 4;
#pragma unroll
  for (int fc = 0; fc < 8; ++fc) {
    int col = fc * 16 + l16;
#pragma unroll
    for (int j = 0; j < 4; ++j) {
      int r = rbase + j;
      if (r < N) h[(size_t)r * F_H + col] = f2bf(acc[fc][j]);
    }
  }
}

// ---------------- layer-1 agg: bf16 gather, 16 lanes/node, +bias+ReLU ------
__global__ void k_agg1(const unsigned short* __restrict__ h, const float* __restrict__ dinv,
                       const int* __restrict__ rp, const int* __restrict__ srcs,
                       const float* __restrict__ bias, unsigned short* __restrict__ out, int N) {
  int gid = blockIdx.x * blockDim.x + threadIdx.x;
  int n = gid >> 4;
  if (n >= N) return;
  const int lane = threadIdx.x & 63;
  const int l16 = lane & 15;
  const int gbase = lane & 48;
  const int f = l16 * 8;

  float dn = dinv[n];
  float acc[8], tmp[8];
  uint4 sv = *(const uint4*)(h + (size_t)n * F_H + f);
  bf8_to_f32(sv, tmp);
  float sl = dn * dn;
#pragma unroll
  for (int i = 0; i < 8; ++i) acc[i] = tmp[i] * sl;

  int beg = rp[n], end = rp[n + 1];
  for (int jb = beg; jb < end; jb += 16) {
    int lim = end - jb; if (lim > 16) lim = 16;
    int sidx = srcs[jb + ((l16 < lim) ? l16 : 0)];
    float sdv = dinv[sidx];

    if (lim == 16) {
#pragma unroll
      for (int i = 0; i < 16; ++i) {
        int s = __shfl(sidx, gbase + i);
        float nr = __shfl(sdv, gbase + i) * dn;
        uint4 hv = *(const uint4*)(h + (size_t)s * F_H + f);
        bf8_to_f32(hv, tmp);
#pragma unroll
        for (int q = 0; q < 8; ++q) acc[q] += tmp[q] * nr;
      }
    } else {
      for (int i = 0; i < lim; ++i) {
        int s = __shfl(sidx, gbase + i);
        float nr = __shfl(sdv, gbase + i) * dn;
        uint4 hv = *(const uint4*)(h + (size_t)s * F_H + f);
        bf8_to_f32(hv, tmp);
#pragma unroll
        for (int q = 0; q < 8; ++q) acc[q] += tmp[q] * nr;
      }
    }
  }

#pragma unroll
  for (int i = 0; i < 8; ++i) {
    acc[i] += bias[f + i];
    acc[i] = fmaxf(acc[i], 0.f);
  }
  uint4 o;
  o.x = f2bf(acc[0]) | ((unsigned)f2bf(acc[1]) << 16);
  o.y = f2bf(acc[2]) | ((unsigned)f2bf(acc[3]) << 16);
  o.z = f2bf(acc[4]) | ((unsigned)f2bf(acc[5]) << 16);
  o.w = f2bf(acc[6]) | ((unsigned)f2bf(acc[7]) << 16);
  *(uint4*)(out + (size_t)n * F_H + f) = o;
}

// ---------------- GEMM2 (MFMA bf16): h2 = a1 @ W2 -> bf16 [N][64] ----------
__global__ __launch_bounds__(256) void k_gemm2(const unsigned short* __restrict__ a,
                                               const unsigned short* __restrict__ W2t,
                                               unsigned short* __restrict__ h2, int N) {
  const int t = threadIdx.x, lane = t & 63, w = t >> 6;
  const int l16 = lane & 15, g = lane >> 4;
  const int row0 = blockIdx.x * 128 + w * 32;

  short8 bfr[3][4];
#pragma unroll
  for (int fc = 0; fc < 3; ++fc)
#pragma unroll
    for (int ks = 0; ks < 4; ++ks)
      bfr[fc][ks] = *(const short8*)(W2t + (size_t)(fc * 16 + l16) * F_H + ks * 32 + g * 8);

  f32x4 acc[2][3];
#pragma unroll
  for (int i = 0; i < 2; ++i)
#pragma unroll
    for (int j = 0; j < 3; ++j) acc[i][j] = (f32x4){0.f, 0.f, 0.f, 0.f};

  short8 af[2][4];
#pragma unroll
  for (int fr = 0; fr < 2; ++fr) {
    int r = row0 + fr * 16 + l16; if (r >= N) r = N - 1;
#pragma unroll
    for (int ks = 0; ks < 4; ++ks)
      af[fr][ks] = *(const short8*)(a + (size_t)r * F_H + ks * 32 + g * 8);
  }

#pragma unroll
  for (int fr = 0; fr < 2; ++fr)
#pragma unroll
    for (int ks = 0; ks < 4; ++ks)
#pragma unroll
      for (int fc = 0; fc < 3; ++fc)
        acc[fr][fc] = __builtin_amdgcn_mfma_f32_16x16x32_bf16(af[fr][ks], bfr[fc][ks], acc[fr][fc], 0, 0, 0);

#pragma unroll
  for (int fr = 0; fr < 2; ++fr) {
    int rbase = row0 + fr * 16 + g * 4;
#pragma unroll
    for (int j = 0; j < 4; ++j) {
      int r = rbase + j;
      if (r >= N) continue;
#pragma unroll
      for (int fc = 0; fc < 3; ++fc)
        h2[(size_t)r * F_PAD + fc * 16 + l16] = f2bf(acc[fr][fc][j]);
      h2[(size_t)r * F_PAD + 48 + l16] = 0;   // zero pad cols 48..63
    }
  }
}

// ---------------- layer-2 agg + b2 + log_softmax fused ---------------------
// 8 lanes/node; gather 128B rows of h2 (bf16[64]); softmax over the 8-lane
// group via shfl_xor; lanes 0..4 write the 40 f32 outputs.
__global__ void k_agg2sm(const unsigned short* __restrict__ h2, const float* __restrict__ dinv,
                         const int* __restrict__ rp, const int* __restrict__ srcs,
                         const float* __restrict__ b2, float* __restrict__ out, int N) {
  int gid = blockIdx.x * blockDim.x + threadIdx.x;
  int n = gid >> 3;
  if (n >= N) return;
  const int lane = threadIdx.x & 63;
  const int l8 = lane & 7;
  const int gb = lane & 56;
  const int f = l8 * 8;

  float dn = dinv[n];
  float acc[8], tmp[8];
  uint4 sv = *(const uint4*)(h2 + (size_t)n * F_PAD + f);
  bf8_to_f32(sv, tmp);
  float sl = dn * dn;
#pragma unroll
  for (int i = 0; i < 8; ++i) acc[i] = tmp[i] * sl;

  int beg = rp[n], end = rp[n + 1];
  for (int jb = beg; jb < end; jb += 8) {
    int lim = end - jb; if (lim > 8) lim = 8;
    int sidx = srcs[jb + ((l8 < lim) ? l8 : 0)];
    float sdv = dinv[sidx];

    if (lim == 8) {
#pragma unroll
      for (int i = 0; i < 8; ++i) {
        int s = __shfl(sidx, gb + i);
        float nr = __shfl(sdv, gb + i) * dn;
        uint4 hv = *(const uint4*)(h2 + (size_t)s * F_PAD + f);
        bf8_to_f32(hv, tmp);
#pragma unroll
        for (int q = 0; q < 8; ++q) acc[q] += tmp[q] * nr;
      }
    } else {
      for (int i = 0; i < lim; ++i) {
        int s = __shfl(sidx, gb + i);
        float nr = __shfl(sdv, gb + i) * dn;
        uint4 hv = *(const uint4*)(h2 + (size_t)s * F_PAD + f);
        bf8_to_f32(hv, tmp);
#pragma unroll
        for (int q = 0; q < 8; ++q) acc[q] += tmp[q] * nr;
      }
    }
  }

  // + b2, masked log_softmax over 40 cols
  float vals[8];
  float m = -3.0e38f;
#pragma unroll
  for (int q = 0; q < 8; ++q) {
    int col = f + q;
    if (col < F_OUT) {
      vals[q] = acc[q] + b2[col];
      m = fmaxf(m, vals[q]);
    } else {
      vals[q] = -3.0e38f;
    }
  }
#pragma unroll
  for (int off = 4; off > 0; off >>= 1) m = fmaxf(m, __shfl_xor(m, off));
  float e = 0.f;
#pragma unroll
  for (int q = 0; q < 8; ++q) {
    int col = f + q;
    if (col < F_OUT) e += expf(vals[q] - m);
  }
#pragma unroll
  for (int off = 4; off > 0; off >>= 1) e += __shfl_xor(e, off);
  float ls = logf(e) + m;

  if (l8 < 5) {
    float4 o0 = {vals[0] - ls, vals[1] - ls, vals[2] - ls, vals[3] - ls};
    float4 o1 = {vals[4] - ls, vals[5] - ls, vals[6] - ls, vals[7] - ls};
    float* op = out + (size_t)n * F_OUT + f;
    *(float4*)op = o0;
    *(float4*)(op + 4) = o1;
  }
}

extern "C" void kernel_launch(void* const* d_in, const int* in_sizes, int n_in,
                              void* d_out, int out_size, void* d_ws, size_t ws_size,
                              hipStream_t stream) {
  const float* x  = (const float*)d_in[0];
  const int*   ei = (const int*)d_in[1];
  const float* W1 = (const float*)d_in[2];
  const float* b1 = (const float*)d_in[3];
  const float* W2 = (const float*)d_in[4];
  const float* b2 = (const float*)d_in[5];

  const int N = in_sizes[0] / F_IN;   // 50000
  const int E = in_sizes[1] / 2;      // 800000
  const int* src = ei;
  const int* dst = ei + E;

  // workspace layout (4-byte words)
  float* ws   = (float*)d_ws;
  size_t Npad = ((size_t)N + 1023) & ~(size_t)1023;
  float*          dinv   = ws;
  unsigned short* h1b    = (unsigned short*)(ws + Npad);          // N*128 bf16
  unsigned short* a1b    = h1b + (size_t)N * F_H;                 // N*128 bf16
  unsigned short* h2b    = a1b + (size_t)N * F_H;                 // N*64 bf16
  int*            cnt    = (int*)(h2b + (size_t)N * F_PAD);
  int*            row_ptr= cnt + Npad;
  int*            cursor = row_ptr + Npad;
  int*            src_sorted = cursor + Npad;
  unsigned short* W1t    = (unsigned short*)(src_sorted + E);     // 128*512 bf16
  unsigned short* W2t    = W1t + (size_t)F_H * F_IN;              // 48*128 bf16
  int*            bsum   = (int*)(W2t + (size_t)F_OP * F_H);
  float*          outp   = (float*)d_out;

  const int B = 256;
  const int nscan = (N + 1023) / 1024;   // 49

  hipMemsetAsync(cnt, 0, (size_t)N * sizeof(int), stream);
  k_count     <<<(E + B - 1) / B, B, 0, stream>>>(dst, cnt, E);
  k_scan_local<<<nscan, 1024, 0, stream>>>(cnt, row_ptr, bsum, N);
  k_scan_add  <<<(N + 1 + B - 1) / B, B, 0, stream>>>(row_ptr, bsum, cnt, cursor, dinv, N, E, nscan);
  k_scatter   <<<(E + B - 1) / B, B, 0, stream>>>(src, dst, cursor, src_sorted, E);

  k_wconv<<<(F_H * F_IN + F_OP * F_H + B - 1) / B, B, 0, stream>>>(W1, W2, W1t, W2t);

  // layer 1
  k_gemm1<<<(N + 63) / 64, 256, 0, stream>>>(x, W1t, h1b, N);
  {
    long long threads = (long long)N * 16;
    k_agg1<<<(int)((threads + B - 1) / B), B, 0, stream>>>(h1b, dinv, row_ptr, src_sorted, b1, a1b, N);
  }

  // layer 2: GEMM first (A(a1 W2) == (A a1) W2), then agg + b2 + log_softmax
  k_gemm2<<<(N + 127) / 128, 256, 0, stream>>>(a1b, W2t, h2b, N);
  {
    long long threads = (long long)N * 8;
    k_agg2sm<<<(int)((threads + B - 1) / B), B, 0, stream>>>(h2b, dinv, row_ptr, src_sorted, b2, outp, N);
  }
}

// Round 9
// 179.052 us; speedup vs baseline: 1.5722x; 1.1697x over previous
//
#include <hip/hip_runtime.h>
#include <hip/hip_bf16.h>
#include <hip/hip_fp8.h>
#include <cstddef>
#include <cstdint>

typedef __attribute__((ext_vector_type(8))) short short8;
typedef __attribute__((ext_vector_type(4))) float f32x4;
typedef __attribute__((ext_vector_type(2))) float f32x2;

static constexpr int F_IN  = 512;
static constexpr int F_H   = 128;
static constexpr int F_OUT = 40;
static constexpr int F_OP  = 48;   // padded cols for gemm2 MFMA
static constexpr int H2B   = 48;   // h2 row stride in bytes (fp8)

__device__ inline unsigned short f2bf(float f) {
  return __builtin_bit_cast(unsigned short, __float2bfloat16(f));
}
__device__ inline float bf2f(uint32_t lo16) {
  return __builtin_bit_cast(float, lo16 << 16);
}
__device__ inline void bf8_to_f32(uint4 u, float* o) {
  o[0] = bf2f(u.x & 0xFFFFu); o[1] = bf2f(u.x >> 16);
  o[2] = bf2f(u.y & 0xFFFFu); o[3] = bf2f(u.y >> 16);
  o[4] = bf2f(u.z & 0xFFFFu); o[5] = bf2f(u.z >> 16);
  o[6] = bf2f(u.w & 0xFFFFu); o[7] = bf2f(u.w >> 16);
}
__device__ inline void gload_lds16(const void* g, void* l) {
  __builtin_amdgcn_global_load_lds(
      (const __attribute__((address_space(1))) void*)g,
      (__attribute__((address_space(3))) void*)l, 16, 0, 0);
}

// ---------------- fp8 e4m3 (OCP on gfx950) helpers ----------------
#if __has_builtin(__builtin_amdgcn_cvt_pk_fp8_f32) && __has_builtin(__builtin_amdgcn_cvt_pk_f32_fp8)
#define FP8_HW 1
#else
#define FP8_HW 0
#endif

// pack two floats -> two fp8 bytes (low 16 bits of result)
__device__ inline uint32_t f2fp8x2(float a, float b) {
#if FP8_HW
  return (uint32_t)__builtin_amdgcn_cvt_pk_fp8_f32(a, b, 0, false) & 0xFFFFu;
#else
  __hip_fp8_e4m3 ta(a), tb(b);
  return (uint32_t)ta.__x | ((uint32_t)tb.__x << 8);
#endif
}

// 8 fp8 bytes (uint2) -> 8 floats
__device__ inline void fp8x8_to_f32(uint2 u, float* o) {
#if FP8_HW
  f32x2 p0 = __builtin_amdgcn_cvt_pk_f32_fp8(u.x, false);
  f32x2 p1 = __builtin_amdgcn_cvt_pk_f32_fp8(u.x, true);
  f32x2 p2 = __builtin_amdgcn_cvt_pk_f32_fp8(u.y, false);
  f32x2 p3 = __builtin_amdgcn_cvt_pk_f32_fp8(u.y, true);
  o[0] = p0[0]; o[1] = p0[1]; o[2] = p1[0]; o[3] = p1[1];
  o[4] = p2[0]; o[5] = p2[1]; o[6] = p3[0]; o[7] = p3[1];
#else
  uint32_t w[2] = {u.x, u.y};
#pragma unroll
  for (int i = 0; i < 8; ++i) {
    __hip_fp8_e4m3 t; t.__x = (uint8_t)((w[i >> 2] >> ((i & 3) * 8)) & 0xFF);
    o[i] = (float)t;
  }
#endif
}

// ---------------- CSR build ----------------
__global__ void k_count(const int* __restrict__ dst, int* __restrict__ cnt, int E) {
  int e = blockIdx.x * blockDim.x + threadIdx.x;
  if (e < E) atomicAdd(&cnt[dst[e]], 1);
}

__global__ void k_scan_local(const int* __restrict__ cnt, int* __restrict__ rp,
                             int* __restrict__ bsum, int N) {
  __shared__ int tmp[1024];
  int t = threadIdx.x;
  int i = blockIdx.x * 1024 + t;
  int v = (i < N) ? cnt[i] : 0;
  tmp[t] = v;
  __syncthreads();
  for (int off = 1; off < 1024; off <<= 1) {
    int u = (t >= off) ? tmp[t - off] : 0;
    __syncthreads();
    tmp[t] += u;
    __syncthreads();
  }
  if (i < N) rp[i] = tmp[t] - v;
  if (t == 1023) bsum[blockIdx.x] = tmp[1023];
}

__global__ void k_scan_add(int* __restrict__ rp, const int* __restrict__ bsum,
                           const int* __restrict__ cnt, int* __restrict__ cursor,
                           float* __restrict__ dinv, int N, int E, int nb) {
  __shared__ int sb[64];
  int t = threadIdx.x;
  if (t < 64) {
    int v = (t < nb) ? bsum[t] : 0;
    int orig = v;
#pragma unroll
    for (int off = 1; off < 64; off <<= 1) {
      int u = __shfl_up(v, off);
      if ((t & 63) >= off) v += u;
    }
    sb[t] = v - orig;
  }
  __syncthreads();
  int i = blockIdx.x * blockDim.x + t;
  if (i < N) {
    int r = rp[i] + sb[i >> 10];
    rp[i] = r;
    cursor[i] = r;
    dinv[i] = rsqrtf((float)cnt[i] + 1.0f);
  }
  if (i == N) rp[N] = E;
}

__global__ void k_scatter(const int* __restrict__ src, const int* __restrict__ dst,
                          int* __restrict__ cursor, int* __restrict__ src_sorted, int E) {
  int e = blockIdx.x * blockDim.x + threadIdx.x;
  if (e >= E) return;
  int d = dst[e];
  int pos = atomicAdd(&cursor[d], 1);
  src_sorted[pos] = src[e];
}

// ---------------- weights: W1->W1t[128][512] bf16, W2->W2t[48][128] bf16 ----
__global__ void k_wconv(const float* __restrict__ W1, const float* __restrict__ W2,
                        unsigned short* __restrict__ W1t, unsigned short* __restrict__ W2t) {
  int i = blockIdx.x * blockDim.x + threadIdx.x;
  if (i < F_H * F_IN) {
    int f = i >> 9, k = i & 511;
    W1t[i] = f2bf(W1[(size_t)k * F_H + f]);
  } else {
    int j = i - F_H * F_IN;
    if (j < F_OP * F_H) {
      int c = j >> 7, k = j & 127;
      float v = (c < F_OUT) ? W2[(size_t)k * F_OUT + c] : 0.f;
      W2t[j] = f2bf(v);
    }
  }
}

// ---------------- GEMM1 (MFMA bf16): h = x @ W1 -> fp8 [N][128] ------------
__global__ __launch_bounds__(256) void k_gemm1(const float* __restrict__ x,
                                               const unsigned short* __restrict__ Wt,
                                               unsigned char* __restrict__ h, int N) {
  __shared__ unsigned short Bt[2][128][64];   // 32 KB
  const int t = threadIdx.x, lane = t & 63, w = t >> 6;
  const int l16 = lane & 15, g = lane >> 4;
  const int row0 = blockIdx.x * 64;

  int bsrow[4], bslc[4];
#pragma unroll
  for (int r = 0; r < 4; ++r) {
    int rg = r * 32 + w * 8;
    bsrow[r] = rg + (lane >> 3);
    bslc[r]  = (lane & 7) ^ (bsrow[r] & 7);
  }

  int ar = row0 + w * 16 + l16; if (ar >= N) ar = N - 1;
  const float* ap = x + (size_t)ar * F_IN + g * 8;

  f32x4 acc[8];
#pragma unroll
  for (int j = 0; j < 8; ++j) acc[j] = (f32x4){0.f, 0.f, 0.f, 0.f};

  auto issueB = [&](int buf, int k0) {
#pragma unroll
    for (int r = 0; r < 4; ++r)
      gload_lds16(Wt + (size_t)bsrow[r] * F_IN + k0 + bslc[r] * 8,
                  &Bt[buf][r * 32 + w * 8][0]);
  };

  issueB(0, 0);
  __syncthreads();

  for (int kt = 0; kt < 8; ++kt) {
    const int cur = kt & 1;
    if (kt < 7) issueB(cur ^ 1, (kt + 1) * 64);

    short8 af[2];
#pragma unroll
    for (int ks = 0; ks < 2; ++ks) {
      const float* p = ap + kt * 64 + ks * 32;
      float4 lo = *(const float4*)p;
      float4 hi = *(const float4*)(p + 4);
      short8 v;
      v[0] = (short)f2bf(lo.x); v[1] = (short)f2bf(lo.y);
      v[2] = (short)f2bf(lo.z); v[3] = (short)f2bf(lo.w);
      v[4] = (short)f2bf(hi.x); v[5] = (short)f2bf(hi.y);
      v[6] = (short)f2bf(hi.z); v[7] = (short)f2bf(hi.w);
      af[ks] = v;
    }

#pragma unroll
    for (int ks = 0; ks < 2; ++ks) {
      const int lcf = ks * 4 + g;
      short8 bfr[8];
#pragma unroll
      for (int fc = 0; fc < 8; ++fc) {
        int rr = fc * 16 + l16;
        bfr[fc] = *(const short8*)&Bt[cur][rr][(lcf ^ (rr & 7)) * 8];
      }
#pragma unroll
      for (int fc = 0; fc < 8; ++fc)
        acc[fc] = __builtin_amdgcn_mfma_f32_16x16x32_bf16(af[ks], bfr[fc], acc[fc], 0, 0, 0);
    }
    __syncthreads();
  }

  // C write as fp8: col = fc*16 + l16, row = row0 + w*16 + g*4 + j
  int rbase = row0 + w * 16 + g * 4;
#pragma unroll
  for (int fc = 0; fc < 8; ++fc) {
    int col = fc * 16 + l16;
#pragma unroll
    for (int jp = 0; jp < 2; ++jp) {         // rows in pairs to share cvt_pk
      uint32_t pk = f2fp8x2(acc[fc][jp * 2], acc[fc][jp * 2 + 1]);
      int r0 = rbase + jp * 2;
      if (r0 < N)     h[(size_t)r0 * F_H + col]       = (unsigned char)(pk & 0xFF);
      if (r0 + 1 < N) h[(size_t)(r0 + 1) * F_H + col] = (unsigned char)(pk >> 8);
    }
  }
}

// ---------------- layer-1 agg: fp8 gather, 16 lanes/node, +bias+ReLU -------
// out a1 stays bf16 (sequential gemm2 input).
__global__ void k_agg1(const unsigned char* __restrict__ h, const float* __restrict__ dinv,
                       const int* __restrict__ rp, const int* __restrict__ srcs,
                       const float* __restrict__ bias, unsigned short* __restrict__ out, int N) {
  int gid = blockIdx.x * blockDim.x + threadIdx.x;
  int n = gid >> 4;
  if (n >= N) return;
  const int lane = threadIdx.x & 63;
  const int l16 = lane & 15;
  const int gbase = lane & 48;
  const int f = l16 * 8;

  float dn = dinv[n];
  float acc[8], tmp[8];
  uint2 sv = *(const uint2*)(h + (size_t)n * F_H + f);
  fp8x8_to_f32(sv, tmp);
  float sl = dn * dn;
#pragma unroll
  for (int i = 0; i < 8; ++i) acc[i] = tmp[i] * sl;

  int beg = rp[n], end = rp[n + 1];
  for (int jb = beg; jb < end; jb += 16) {
    int lim = end - jb; if (lim > 16) lim = 16;
    int sidx = srcs[jb + ((l16 < lim) ? l16 : 0)];
    float sdv = dinv[sidx];

    if (lim == 16) {
#pragma unroll
      for (int i = 0; i < 16; ++i) {
        int s = __shfl(sidx, gbase + i);
        float nr = __shfl(sdv, gbase + i) * dn;
        uint2 hv = *(const uint2*)(h + (size_t)s * F_H + f);
        fp8x8_to_f32(hv, tmp);
#pragma unroll
        for (int q = 0; q < 8; ++q) acc[q] += tmp[q] * nr;
      }
    } else {
      for (int i = 0; i < lim; ++i) {
        int s = __shfl(sidx, gbase + i);
        float nr = __shfl(sdv, gbase + i) * dn;
        uint2 hv = *(const uint2*)(h + (size_t)s * F_H + f);
        fp8x8_to_f32(hv, tmp);
#pragma unroll
        for (int q = 0; q < 8; ++q) acc[q] += tmp[q] * nr;
      }
    }
  }

#pragma unroll
  for (int i = 0; i < 8; ++i) {
    acc[i] += bias[f + i];
    acc[i] = fmaxf(acc[i], 0.f);
  }
  uint4 o;
  o.x = f2bf(acc[0]) | ((unsigned)f2bf(acc[1]) << 16);
  o.y = f2bf(acc[2]) | ((unsigned)f2bf(acc[3]) << 16);
  o.z = f2bf(acc[4]) | ((unsigned)f2bf(acc[5]) << 16);
  o.w = f2bf(acc[6]) | ((unsigned)f2bf(acc[7]) << 16);
  *(uint4*)(out + (size_t)n * F_H + f) = o;
}

// ---------------- GEMM2 (MFMA bf16): h2 = a1 @ W2 -> fp8 [N][48B] ----------
__global__ __launch_bounds__(256) void k_gemm2(const unsigned short* __restrict__ a,
                                               const unsigned short* __restrict__ W2t,
                                               unsigned char* __restrict__ h2, int N) {
  const int t = threadIdx.x, lane = t & 63, w = t >> 6;
  const int l16 = lane & 15, g = lane >> 4;
  const int row0 = blockIdx.x * 128 + w * 32;

  short8 bfr[3][4];
#pragma unroll
  for (int fc = 0; fc < 3; ++fc)
#pragma unroll
    for (int ks = 0; ks < 4; ++ks)
      bfr[fc][ks] = *(const short8*)(W2t + (size_t)(fc * 16 + l16) * F_H + ks * 32 + g * 8);

  f32x4 acc[2][3];
#pragma unroll
  for (int i = 0; i < 2; ++i)
#pragma unroll
    for (int j = 0; j < 3; ++j) acc[i][j] = (f32x4){0.f, 0.f, 0.f, 0.f};

  short8 af[2][4];
#pragma unroll
  for (int fr = 0; fr < 2; ++fr) {
    int r = row0 + fr * 16 + l16; if (r >= N) r = N - 1;
#pragma unroll
    for (int ks = 0; ks < 4; ++ks)
      af[fr][ks] = *(const short8*)(a + (size_t)r * F_H + ks * 32 + g * 8);
  }

#pragma unroll
  for (int fr = 0; fr < 2; ++fr)
#pragma unroll
    for (int ks = 0; ks < 4; ++ks)
#pragma unroll
      for (int fc = 0; fc < 3; ++fc)
        acc[fr][fc] = __builtin_amdgcn_mfma_f32_16x16x32_bf16(af[fr][ks], bfr[fc][ks], acc[fr][fc], 0, 0, 0);

#pragma unroll
  for (int fr = 0; fr < 2; ++fr) {
    int rbase = row0 + fr * 16 + g * 4;
#pragma unroll
    for (int fc = 0; fc < 3; ++fc) {
      int col = fc * 16 + l16;
#pragma unroll
      for (int jp = 0; jp < 2; ++jp) {
        uint32_t pk = f2fp8x2(acc[fr][fc][jp * 2], acc[fr][fc][jp * 2 + 1]);
        int r0 = rbase + jp * 2;
        if (r0 < N)     h2[(size_t)r0 * H2B + col]       = (unsigned char)(pk & 0xFF);
        if (r0 + 1 < N) h2[(size_t)(r0 + 1) * H2B + col] = (unsigned char)(pk >> 8);
      }
    }
  }
}

// ---------------- layer-2 agg + b2 + log_softmax fused ---------------------
// 8 lanes/node; lanes 0..4 gather 8 fp8 cols each (40B/row); shfl softmax.
__global__ void k_agg2sm(const unsigned char* __restrict__ h2, const float* __restrict__ dinv,
                         const int* __restrict__ rp, const int* __restrict__ srcs,
                         const float* __restrict__ b2, float* __restrict__ out, int N) {
  int gid = blockIdx.x * blockDim.x + threadIdx.x;
  int n = gid >> 3;
  if (n >= N) return;
  const int lane = threadIdx.x & 63;
  const int l8 = lane & 7;
  const int gb = lane & 56;
  const int f = l8 * 8;
  const bool live = (l8 < 5);

  float dn = dinv[n];
  float acc[8], tmp[8];
#pragma unroll
  for (int i = 0; i < 8; ++i) acc[i] = 0.f;
  if (live) {
    uint2 sv = *(const uint2*)(h2 + (size_t)n * H2B + f);
    fp8x8_to_f32(sv, tmp);
    float sl = dn * dn;
#pragma unroll
    for (int i = 0; i < 8; ++i) acc[i] = tmp[i] * sl;
  }

  int beg = rp[n], end = rp[n + 1];
  for (int jb = beg; jb < end; jb += 8) {
    int lim = end - jb; if (lim > 8) lim = 8;
    int sidx = srcs[jb + ((l8 < lim) ? l8 : 0)];
    float sdv = dinv[sidx];

    for (int i = 0; i < lim; ++i) {
      int s = __shfl(sidx, gb + i);
      float nr = __shfl(sdv, gb + i) * dn;
      if (live) {
        uint2 hv = *(const uint2*)(h2 + (size_t)s * H2B + f);
        fp8x8_to_f32(hv, tmp);
#pragma unroll
        for (int q = 0; q < 8; ++q) acc[q] += tmp[q] * nr;
      }
    }
  }

  // + b2, masked log_softmax over 40 cols
  float vals[8];
  float m = -3.0e38f;
#pragma unroll
  for (int q = 0; q < 8; ++q) {
    int col = f + q;
    if (col < F_OUT) {
      vals[q] = acc[q] + b2[col];
      m = fmaxf(m, vals[q]);
    } else {
      vals[q] = -3.0e38f;
    }
  }
#pragma unroll
  for (int off = 4; off > 0; off >>= 1) m = fmaxf(m, __shfl_xor(m, off));
  float e = 0.f;
#pragma unroll
  for (int q = 0; q < 8; ++q) {
    int col = f + q;
    if (col < F_OUT) e += expf(vals[q] - m);
  }
#pragma unroll
  for (int off = 4; off > 0; off >>= 1) e += __shfl_xor(e, off);
  float ls = logf(e) + m;

  if (live) {
    float4 o0 = {vals[0] - ls, vals[1] - ls, vals[2] - ls, vals[3] - ls};
    float4 o1 = {vals[4] - ls, vals[5] - ls, vals[6] - ls, vals[7] - ls};
    float* op = out + (size_t)n * F_OUT + f;
    *(float4*)op = o0;
    *(float4*)(op + 4) = o1;
  }
}

extern "C" void kernel_launch(void* const* d_in, const int* in_sizes, int n_in,
                              void* d_out, int out_size, void* d_ws, size_t ws_size,
                              hipStream_t stream) {
  const float* x  = (const float*)d_in[0];
  const int*   ei = (const int*)d_in[1];
  const float* W1 = (const float*)d_in[2];
  const float* b1 = (const float*)d_in[3];
  const float* W2 = (const float*)d_in[4];
  const float* b2 = (const float*)d_in[5];

  const int N = in_sizes[0] / F_IN;   // 50000
  const int E = in_sizes[1] / 2;      // 800000
  const int* src = ei;
  const int* dst = ei + E;

  // workspace layout (byte-addressed, 256B-aligned chunks)
  char* base = (char*)d_ws;
  auto alloc = [&](size_t bytes) {
    char* p = base;
    base += (bytes + 255) & ~(size_t)255;
    return p;
  };
  size_t Npad = ((size_t)N + 1023) & ~(size_t)1023;
  float*          dinv    = (float*)alloc(Npad * 4);
  unsigned char*  h1      = (unsigned char*)alloc((size_t)N * F_H);        // fp8
  unsigned short* a1b     = (unsigned short*)alloc((size_t)N * F_H * 2);   // bf16
  unsigned char*  h2      = (unsigned char*)alloc((size_t)N * H2B);        // fp8
  int*            cnt     = (int*)alloc(Npad * 4);
  int*            row_ptr = (int*)alloc((Npad + 64) * 4);
  int*            cursor  = (int*)alloc(Npad * 4);
  int*            src_sorted = (int*)alloc((size_t)E * 4);
  unsigned short* W1t     = (unsigned short*)alloc((size_t)F_H * F_IN * 2);
  unsigned short* W2t     = (unsigned short*)alloc((size_t)F_OP * F_H * 2);
  int*            bsum    = (int*)alloc(64 * 4);
  float*          outp    = (float*)d_out;

  const int B = 256;
  const int nscan = (N + 1023) / 1024;   // 49

  hipMemsetAsync(cnt, 0, (size_t)N * sizeof(int), stream);
  k_count     <<<(E + B - 1) / B, B, 0, stream>>>(dst, cnt, E);
  k_scan_local<<<nscan, 1024, 0, stream>>>(cnt, row_ptr, bsum, N);
  k_scan_add  <<<(N + 1 + B - 1) / B, B, 0, stream>>>(row_ptr, bsum, cnt, cursor, dinv, N, E, nscan);
  k_scatter   <<<(E + B - 1) / B, B, 0, stream>>>(src, dst, cursor, src_sorted, E);

  k_wconv<<<(F_H * F_IN + F_OP * F_H + B - 1) / B, B, 0, stream>>>(W1, W2, W1t, W2t);

  // layer 1
  k_gemm1<<<(N + 63) / 64, 256, 0, stream>>>(x, W1t, h1, N);
  {
    long long threads = (long long)N * 16;
    k_agg1<<<(int)((threads + B - 1) / B), B, 0, stream>>>(h1, dinv, row_ptr, src_sorted, b1, a1b, N);
  }

  // layer 2: GEMM first, then agg + b2 + log_softmax
  k_gemm2<<<(N + 127) / 128, 256, 0, stream>>>(a1b, W2t, h2, N);
  {
    long long threads = (long long)N * 8;
    k_agg2sm<<<(int)((threads + B - 1) / B), B, 0, stream>>>(h2, dinv, row_ptr, src_sorted, b2, outp, N);
  }
}